// Round 11
// baseline (171.446 us; speedup 1.0000x reference)
//
#include <hip/hip_runtime.h>
#include <hip/hip_bf16.h>

#define S_DIM 128
#define R_DIM 256
#define CM 256
#define CZ 128
#define H_DIM 8
#define C_DIM 32

typedef short bf16x8 __attribute__((ext_vector_type(8)));
typedef float f32x4 __attribute__((ext_vector_type(4)));

__device__ inline ushort f2b(float f) {
  __hip_bfloat16 b = __float2bfloat16(f);
  return *(ushort*)&b;
}
__device__ inline float b2f(ushort u) {
  __hip_bfloat16 b = *(__hip_bfloat16*)&u;
  return __bfloat162float(b);
}

// async global->LDS, 16 B per lane; LDS dest is wave-uniform base + lane*16
__device__ __forceinline__ void gld_lds16(const ushort* g, ushort* l) {
  __builtin_amdgcn_global_load_lds(
      (const __attribute__((address_space(1))) unsigned int*)g,
      (__attribute__((address_space(3))) unsigned int*)l, 16, 0, 0);
}

// ---------------- Kernel 0: weight transpose f32 -> bf16 ----------------
__global__ __launch_bounds__(256) void wt_kernel(
    const float* __restrict__ wq, const float* __restrict__ wk,
    const float* __restrict__ wv, const float* __restrict__ wg,
    const float* __restrict__ wo, ushort* __restrict__ Wt5) {
  __shared__ float t[64][65];
  int z = blockIdx.z;
  const float* W = (z == 0) ? wq : (z == 1) ? wk : (z == 2) ? wv
                   : (z == 3) ? wg : wo;
  ushort* Wt = Wt5 + (size_t)z * 65536;
  int tid = threadIdx.x;
  int r = tid >> 2, c4 = (tid & 3) * 16;
  int rowBase = blockIdx.y * 64, colBase = blockIdx.x * 64;
#pragma unroll
  for (int j = 0; j < 16; ++j)
    t[r][c4 + j] = W[(size_t)(rowBase + r) * 256 + colBase + c4 + j];
  __syncthreads();
#pragma unroll
  for (int j = 0; j < 16; ++j)
    Wt[(size_t)(colBase + r) * 256 + rowBase + c4 + j] = f2b(t[c4 + j][r]);
}

// ------- Kernel 1: LayerNorm of msa -> m (bf16), wave per row ----------
__global__ __launch_bounds__(256) void ln_msa_kernel(
    const float* __restrict__ x, const float* __restrict__ g,
    const float* __restrict__ b, ushort* __restrict__ m) {
  int lane = threadIdx.x & 63, w = threadIdx.x >> 6;
  int row = blockIdx.x * 4 + w;
  const float* xp = x + (size_t)row * CM + lane * 4;
  float4 v = *(const float4*)xp;
  float s1 = v.x + v.y + v.z + v.w;
  float s2 = v.x * v.x + v.y * v.y + v.z * v.z + v.w * v.w;
#pragma unroll
  for (int off = 32; off; off >>= 1) {
    s1 += __shfl_xor(s1, off, 64);
    s2 += __shfl_xor(s2, off, 64);
  }
  float mean = s1 * (1.0f / CM);
  float rstd = rsqrtf(s2 * (1.0f / CM) - mean * mean + 1e-5f);
  float4 gv = *(const float4*)(g + lane * 4);
  float4 bv = *(const float4*)(b + lane * 4);
  ushort4 o;
  o.x = f2b((v.x - mean) * rstd * gv.x + bv.x);
  o.y = f2b((v.y - mean) * rstd * gv.y + bv.y);
  o.z = f2b((v.z - mean) * rstd * gv.z + bv.z);
  o.w = f2b((v.w - mean) * rstd * gv.w + bv.w);
  *(ushort4*)(m + (size_t)row * CM + lane * 4) = o;
}

// ----- Kernel 2: pair LN + bias, 4 lanes per (i,j) row, in-register ----
__global__ __launch_bounds__(256) void pair_bias_kernel(
    const float* __restrict__ z, const float* __restrict__ g,
    const float* __restrict__ b, const float* __restrict__ w_b,
    const float* __restrict__ b_b, float* __restrict__ bias) {
  __shared__ float wbs[CZ][8];
  __shared__ float gs[CZ], bs[CZ];
  int tid = threadIdx.x;
  if (tid < CZ) { gs[tid] = g[tid]; bs[tid] = b[tid]; }
  for (int i = tid; i < CZ * 8; i += 256) wbs[i >> 3][i & 7] = w_b[i];
  __syncthreads();
  int q = tid & 3;
  int row = blockIdx.x * 64 + (tid >> 2);
  const float* zp = z + (size_t)row * CZ + q * 32;
  float4 v[8];
#pragma unroll
  for (int j = 0; j < 8; ++j) v[j] = *(const float4*)(zp + j * 4);
  float s1 = 0.f, s2 = 0.f;
#pragma unroll
  for (int j = 0; j < 8; ++j) {
    s1 += v[j].x + v[j].y + v[j].z + v[j].w;
    s2 += v[j].x * v[j].x + v[j].y * v[j].y + v[j].z * v[j].z +
          v[j].w * v[j].w;
  }
  s1 += __shfl_xor(s1, 1, 64);
  s2 += __shfl_xor(s2, 1, 64);
  s1 += __shfl_xor(s1, 2, 64);
  s2 += __shfl_xor(s2, 2, 64);
  float mean = s1 * (1.0f / CZ);
  float var = s2 * (1.0f / CZ) - mean * mean;
  float rstd = rsqrtf(var + 1e-5f);
  float acc[8] = {};
#pragma unroll
  for (int j = 0; j < 8; ++j) {
    float e[4] = {v[j].x, v[j].y, v[j].z, v[j].w};
#pragma unroll
    for (int u = 0; u < 4; ++u) {
      int c = q * 32 + j * 4 + u;
      float zn = (e[u] - mean) * rstd * gs[c] + bs[c];
#pragma unroll
      for (int h = 0; h < 8; ++h) acc[h] += zn * wbs[c][h];
    }
  }
#pragma unroll
  for (int h = 0; h < 8; ++h) {
    acc[h] += __shfl_xor(acc[h], 1, 64);
    acc[h] += __shfl_xor(acc[h], 2, 64);
  }
  int h0 = q * 2;
  bias[(size_t)h0 * (R_DIM * R_DIM) + row] = acc[h0] + b_b[h0];
  bias[(size_t)(h0 + 1) * (R_DIM * R_DIM) + row] = acc[h0 + 1] + b_b[h0 + 1];
}

// ---- Kernel 3: fused projection GEMM, 128x64 tile for occupancy -------
__global__ __launch_bounds__(256) void proj_mfma(
    const ushort* __restrict__ M, const ushort* __restrict__ Wt5,
    const float* __restrict__ b_g, ushort* __restrict__ qb,
    ushort* __restrict__ kb2, ushort* __restrict__ vb,
    ushort* __restrict__ gb) {
  __shared__ ushort As[128 * 64];
  __shared__ ushort Bs[64 * 64];
  int tid = threadIdx.x, lane = tid & 63, wid = tid >> 6;
  int lr = lane & 15, lg = lane >> 4;
  int rowBase = blockIdx.x * 128;
  int cby = blockIdx.y;             // 0..15; 64 fused cols each
  int proj = cby >> 2;
  int sc = (lane & 7) ^ ((lane >> 3) & 7);   // swizzled source chunk
  const ushort* Ag =
      M + (size_t)(rowBase + wid * 32 + (lane >> 3)) * 256 + sc * 8;
  const ushort* Bg =
      Wt5 + (size_t)(cby * 64 + wid * 16 + (lane >> 3)) * 256 + sc * 8;
  ushort* Asl = As + wid * (32 * 64);
  ushort* Bsl = Bs + wid * (16 * 64);
  int wr = wid >> 1, wc = wid & 1;
  int sx = (lr & 7) * 8;                      // read-side XOR (in ushorts)
  f32x4 zf = {0.f, 0.f, 0.f, 0.f};
  f32x4 acc[4][2];
#pragma unroll
  for (int i = 0; i < 4; ++i)
#pragma unroll
    for (int j = 0; j < 2; ++j) acc[i][j] = zf;

  for (int kb = 0; kb < 4; ++kb) {
    if (kb) __syncthreads();
#pragma unroll
    for (int c = 0; c < 4; ++c)
      gld_lds16(Ag + kb * 64 + c * (8 * 256), Asl + c * (8 * 64));
#pragma unroll
    for (int c = 0; c < 2; ++c)
      gld_lds16(Bg + kb * 64 + c * (8 * 256), Bsl + c * (8 * 64));
    __syncthreads();
#pragma unroll
    for (int kk = 0; kk < 2; ++kk) {
      bf16x8 a[4], b[2];
#pragma unroll
      for (int mf = 0; mf < 4; ++mf)
        a[mf] = *(const bf16x8*)&As[(wr * 64 + mf * 16 + lr) * 64 +
                                    ((kk * 32 + lg * 8) ^ sx)];
#pragma unroll
      for (int nf = 0; nf < 2; ++nf)
        b[nf] = *(const bf16x8*)&Bs[(wc * 32 + nf * 16 + lr) * 64 +
                                    ((kk * 32 + lg * 8) ^ sx)];
#pragma unroll
      for (int mf = 0; mf < 4; ++mf)
#pragma unroll
        for (int nf = 0; nf < 2; ++nf)
          acc[mf][nf] = __builtin_amdgcn_mfma_f32_16x16x32_bf16(
              b[nf], a[mf], acc[mf][nf], 0, 0, 0);   // swapped: C^T
    }
  }
  // epilogue: lane row = rowBase+wr*64+mf*16+lr; 4 consecutive cols
#pragma unroll
  for (int mf = 0; mf < 4; ++mf) {
    int row = rowBase + wr * 64 + mf * 16 + lr;
    int s = row >> 8, rr = row & 255;
#pragma unroll
    for (int nf = 0; nf < 2; ++nf) {
      int colL = (cby & 3) * 64 + wc * 32 + nf * 16 + lg * 4;
      int h = colL >> 5, d0 = colL & 31;
      size_t oidx = ((size_t)((s * H_DIM + h) * R_DIM + rr)) * C_DIM + d0;
      f32x4 v4 = acc[mf][nf];
      ushort4 o4;
      if (proj == 0) {
        o4.x = f2b(v4[0] * 0.17677669529663687f);
        o4.y = f2b(v4[1] * 0.17677669529663687f);
        o4.z = f2b(v4[2] * 0.17677669529663687f);
        o4.w = f2b(v4[3] * 0.17677669529663687f);
        *(ushort4*)(qb + oidx) = o4;
      } else if (proj == 1) {
        o4.x = f2b(v4[0]); o4.y = f2b(v4[1]);
        o4.z = f2b(v4[2]); o4.w = f2b(v4[3]);
        *(ushort4*)(kb2 + oidx) = o4;
      } else if (proj == 2) {
        o4.x = f2b(v4[0]); o4.y = f2b(v4[1]);
        o4.z = f2b(v4[2]); o4.w = f2b(v4[3]);
        *(ushort4*)(vb + oidx) = o4;
      } else {
        float4 bg4 = *(const float4*)(b_g + colL);
        o4.x = f2b(1.f / (1.f + __expf(-(v4[0] + bg4.x))));
        o4.y = f2b(1.f / (1.f + __expf(-(v4[1] + bg4.y))));
        o4.z = f2b(1.f / (1.f + __expf(-(v4[2] + bg4.z))));
        o4.w = f2b(1.f / (1.f + __expf(-(v4[3] + bg4.w))));
        *(ushort4*)(gb + oidx) = o4;
      }
    }
  }
}

// --- Kernel 4: MFMA flash attention per (s,h), 8 waves x 32 q rows ------
// Per-mf pipeline (QK -> softmax -> PV per 16-row half): Pl is 16 rows,
// LDS 33.9 KB -> 4 blocks/CU. Odd-dword strides (266/66) kill conflicts.
__global__ __launch_bounds__(512, 8) void attn_mfma(
    const ushort* __restrict__ q, const ushort* __restrict__ k,
    const ushort* __restrict__ v, const ushort* __restrict__ g,
    const float* __restrict__ bias, ushort* __restrict__ ob) {
  __shared__ ushort Vt[32][266];     // V transposed [d][key], odd-dw pad
  __shared__ ushort Pl[8][16][66];   // per-wave P half-tile [q16][key]
  int blk = blockIdx.x;
  int s = blk >> 3, h = blk & 7;
  int tid = threadIdx.x, lane = tid & 63, w = tid >> 6;
  int lr = lane & 15, lg = lane >> 4;
  size_t base = (size_t)(s * H_DIM + h) * (R_DIM * C_DIM);

  // stage V transposed: 512 threads, each half a key row (16 d)
  {
    int key = tid >> 1, half = (tid & 1) * 16;
    const ushort* vp = v + base + (size_t)key * 32 + half;
    bf16x8 t0 = *(const bf16x8*)vp;
    bf16x8 t1 = *(const bf16x8*)(vp + 8);
#pragma unroll
    for (int j = 0; j < 8; ++j) {
      Vt[half + j][key] = (ushort)t0[j];
      Vt[half + 8 + j][key] = (ushort)t1[j];
    }
  }
  __syncthreads();

  int qrow0 = w * 32;
  bf16x8 qf[2];
#pragma unroll
  for (int mf = 0; mf < 2; ++mf)
    qf[mf] = *(const bf16x8*)(q + base + (size_t)(qrow0 + mf * 16 + lr) * 32 +
                              lg * 8);
  const float* bp0 = bias + ((size_t)h * R_DIM + qrow0 + lg * 4) * R_DIM +
                     lr * 4;

  float lsum[2][4] = {};
  f32x4 of[2][2];
  f32x4 zf = {0.f, 0.f, 0.f, 0.f};
#pragma unroll
  for (int mf = 0; mf < 2; ++mf) {
    of[mf][0] = zf;
    of[mf][1] = zf;
  }

  for (int t = 0; t < 4; ++t) {
    int k0 = t * 64;
    bf16x8 kf[4];
#pragma unroll
    for (int nf = 0; nf < 4; ++nf)
      kf[nf] = *(const bf16x8*)(k + base + (size_t)(k0 + lr * 4 + nf) * 32 +
                                lg * 8);
#pragma unroll
    for (int mf = 0; mf < 2; ++mf) {
      // QK^T for this 16-row half
      f32x4 sf[4];
#pragma unroll
      for (int nf = 0; nf < 4; ++nf)
        sf[nf] =
            __builtin_amdgcn_mfma_f32_16x16x32_bf16(qf[mf], kf[nf], zf, 0, 0, 0);
      float4 bv[4];
#pragma unroll
      for (int r = 0; r < 4; ++r)
        bv[r] = *(const float4*)(bp0 + (size_t)(mf * 16 + r) * R_DIM + k0);
#pragma unroll
      for (int r = 0; r < 4; ++r) {
        float p0 = __expf(sf[0][r] + bv[r].x);
        float p1 = __expf(sf[1][r] + bv[r].y);
        float p2 = __expf(sf[2][r] + bv[r].z);
        float p3 = __expf(sf[3][r] + bv[r].w);
        lsum[mf][r] += (p0 + p1) + (p2 + p3);
        ushort4 pk;
        pk.x = f2b(p0);
        pk.y = f2b(p1);
        pk.z = f2b(p2);
        pk.w = f2b(p3);
        *(ushort4*)&Pl[w][lg * 4 + r][lr * 4] = pk;
      }
      // PV for this half (wave-local LDS transpose, in-order per wave)
#pragma unroll
      for (int kt = 0; kt < 2; ++kt) {
        bf16x8 pf = *(const bf16x8*)&Pl[w][lr][kt * 32 + lg * 8];
        bf16x8 vf0 = *(const bf16x8*)&Vt[lr][k0 + kt * 32 + lg * 8];
        bf16x8 vf1 = *(const bf16x8*)&Vt[16 + lr][k0 + kt * 32 + lg * 8];
        of[mf][0] = __builtin_amdgcn_mfma_f32_16x16x32_bf16(
            vf0, pf, of[mf][0], 0, 0, 0);
        of[mf][1] = __builtin_amdgcn_mfma_f32_16x16x32_bf16(
            vf1, pf, of[mf][1], 0, 0, 0);
      }
    }
  }
  // lsum ladder (uniform over lr), then gather per of-row (= mf*16+lr)
#pragma unroll
  for (int mf = 0; mf < 2; ++mf)
#pragma unroll
    for (int r = 0; r < 4; ++r) {
#pragma unroll
      for (int msk = 1; msk <= 8; msk <<= 1)
        lsum[mf][r] += __shfl_xor(lsum[mf][r], msk, 64);
    }
  int srcl = ((lr >> 2) << 4) + lr;
  float invr[2];
#pragma unroll
  for (int mf = 0; mf < 2; ++mf) {
    float t0 = __shfl(lsum[mf][0], srcl, 64);
    float t1 = __shfl(lsum[mf][1], srcl, 64);
    float t2 = __shfl(lsum[mf][2], srcl, 64);
    float t3 = __shfl(lsum[mf][3], srcl, 64);
    int rb = lr & 3;
    float lv = rb == 0 ? t0 : rb == 1 ? t1 : rb == 2 ? t2 : t3;
    invr[mf] = 1.f / lv;
  }
  // epilogue: vectorized gate+store (ushort4)
#pragma unroll
  for (int mf = 0; mf < 2; ++mf) {
    int row = qrow0 + mf * 16 + lr;
#pragma unroll
    for (int df = 0; df < 2; ++df) {
      int d0 = df * 16 + lg * 4;
      ushort4 g4 = *(const ushort4*)(g + base + (size_t)row * 32 + d0);
      ushort4 o4;
      o4.x = f2b(of[mf][df][0] * invr[mf] * b2f(g4.x));
      o4.y = f2b(of[mf][df][1] * invr[mf] * b2f(g4.y));
      o4.z = f2b(of[mf][df][2] * invr[mf] * b2f(g4.z));
      o4.w = f2b(of[mf][df][3] * invr[mf] * b2f(g4.w));
      *(ushort4*)(ob + ((size_t)(s * R_DIM + row)) * 256 + h * 32 + d0) = o4;
    }
  }
}

// ---- Kernel 5: output GEMM, 128x64 tile for occupancy -----------------
__global__ __launch_bounds__(256) void out_mfma(
    const ushort* __restrict__ A, const ushort* __restrict__ Wt,
    const float* __restrict__ b_o, float* __restrict__ out) {
  __shared__ ushort As[128 * 64];
  __shared__ ushort Bs[64 * 64];
  int tid = threadIdx.x, lane = tid & 63, wid = tid >> 6;
  int lr = lane & 15, lg = lane >> 4;
  int rowBase = blockIdx.x * 128;
  int colBase = blockIdx.y * 64;
  int sc = (lane & 7) ^ ((lane >> 3) & 7);
  const ushort* Ag =
      A + (size_t)(rowBase + wid * 32 + (lane >> 3)) * 256 + sc * 8;
  const ushort* Bg =
      Wt + (size_t)(colBase + wid * 16 + (lane >> 3)) * 256 + sc * 8;
  ushort* Asl = As + wid * (32 * 64);
  ushort* Bsl = Bs + wid * (16 * 64);
  int wr = wid >> 1, wc = wid & 1;
  int sx = (lr & 7) * 8;
  f32x4 zf = {0.f, 0.f, 0.f, 0.f};
  f32x4 acc[4][2];
#pragma unroll
  for (int i = 0; i < 4; ++i)
#pragma unroll
    for (int j = 0; j < 2; ++j) acc[i][j] = zf;

  for (int kb = 0; kb < 4; ++kb) {
    if (kb) __syncthreads();
#pragma unroll
    for (int c = 0; c < 4; ++c)
      gld_lds16(Ag + kb * 64 + c * (8 * 256), Asl + c * (8 * 64));
#pragma unroll
    for (int c = 0; c < 2; ++c)
      gld_lds16(Bg + kb * 64 + c * (8 * 256), Bsl + c * (8 * 64));
    __syncthreads();
#pragma unroll
    for (int kk = 0; kk < 2; ++kk) {
      bf16x8 a[4], b[2];
#pragma unroll
      for (int mf = 0; mf < 4; ++mf)
        a[mf] = *(const bf16x8*)&As[(wr * 64 + mf * 16 + lr) * 64 +
                                    ((kk * 32 + lg * 8) ^ sx)];
#pragma unroll
      for (int nf = 0; nf < 2; ++nf)
        b[nf] = *(const bf16x8*)&Bs[(wc * 32 + nf * 16 + lr) * 64 +
                                    ((kk * 32 + lg * 8) ^ sx)];
#pragma unroll
      for (int mf = 0; mf < 4; ++mf)
#pragma unroll
        for (int nf = 0; nf < 2; ++nf)
          acc[mf][nf] = __builtin_amdgcn_mfma_f32_16x16x32_bf16(
              b[nf], a[mf], acc[mf][nf], 0, 0, 0);   // swapped: C^T
    }
  }
#pragma unroll
  for (int mf = 0; mf < 4; ++mf) {
    int row = rowBase + wr * 64 + mf * 16 + lr;
#pragma unroll
    for (int nf = 0; nf < 2; ++nf) {
      int col0 = colBase + wc * 32 + nf * 16 + lg * 4;
      float4 bo4 = *(const float4*)(b_o + col0);
      float4 o4;
      o4.x = acc[mf][nf][0] + bo4.x;
      o4.y = acc[mf][nf][1] + bo4.y;
      o4.z = acc[mf][nf][2] + bo4.z;
      o4.w = acc[mf][nf][3] + bo4.w;
      *(float4*)(out + (size_t)row * 256 + col0) = o4;
    }
  }
}

extern "C" void kernel_launch(void* const* d_in, const int* in_sizes, int n_in,
                              void* d_out, int out_size, void* d_ws,
                              size_t ws_size, hipStream_t stream) {
  const float* msa      = (const float*)d_in[0];
  const float* pair     = (const float*)d_in[1];
  const float* ln_msa_g = (const float*)d_in[2];
  const float* ln_msa_b = (const float*)d_in[3];
  const float* ln_pr_g  = (const float*)d_in[4];
  const float* ln_pr_b  = (const float*)d_in[5];
  const float* w_q      = (const float*)d_in[6];
  const float* w_k      = (const float*)d_in[7];
  const float* w_v      = (const float*)d_in[8];
  const float* w_g      = (const float*)d_in[9];
  const float* b_g      = (const float*)d_in[10];
  const float* w_b      = (const float*)d_in[11];
  const float* b_b      = (const float*)d_in[12];
  const float* w_o      = (const float*)d_in[13];
  const float* b_o      = (const float*)d_in[14];
  float* out = (float*)d_out;

  char* ws = (char*)d_ws;
  ushort* m   = (ushort*)(ws + 0);            // 16,777,216
  ushort* qb  = (ushort*)(ws + 16777216ull);  // 16,777,216
  ushort* kb  = (ushort*)(ws + 33554432ull);  // 16,777,216
  ushort* vb  = (ushort*)(ws + 50331648ull);  // 16,777,216
  ushort* gb  = (ushort*)(ws + 67108864ull);  // 16,777,216
  float*  bi  = (float*) (ws + 83886080ull);  //  2,097,152
  ushort* ob  = (ushort*)(ws + 85983232ull);  // 16,777,216
  ushort* Wt5 = (ushort*)(ws + 102760448ull); //    655,360

  wt_kernel<<<dim3(4, 4, 5), 256, 0, stream>>>(w_q, w_k, w_v, w_g, w_o, Wt5);
  ln_msa_kernel<<<S_DIM * R_DIM / 4, 256, 0, stream>>>(msa, ln_msa_g,
                                                       ln_msa_b, m);
  pair_bias_kernel<<<R_DIM * R_DIM / 64, 256, 0, stream>>>(
      pair, ln_pr_g, ln_pr_b, w_b, b_b, bi);
  proj_mfma<<<dim3(256, 16), 256, 0, stream>>>(m, Wt5, b_g, qb, kb, vb, gb);
  attn_mfma<<<S_DIM * H_DIM, 512, 0, stream>>>(qb, kb, vb, gb, bi, ob);
  out_mfma<<<dim3(256, 4), 256, 0, stream>>>(ob, Wt5 + 4 * 65536, b_o, out);
}

// Round 12
// 117.514 us; speedup vs baseline: 1.4589x; 1.4589x over previous
//
#include <hip/hip_runtime.h>
#include <hip/hip_bf16.h>

#define S_DIM 128
#define R_DIM 256
#define CM 256
#define CZ 128
#define H_DIM 8
#define C_DIM 32

typedef short bf16x8 __attribute__((ext_vector_type(8)));
typedef float f32x4 __attribute__((ext_vector_type(4)));

__device__ inline ushort f2b(float f) {
  __hip_bfloat16 b = __float2bfloat16(f);
  return *(ushort*)&b;
}
__device__ inline float b2f(ushort u) {
  __hip_bfloat16 b = *(__hip_bfloat16*)&u;
  return __bfloat162float(b);
}

// async global->LDS, 16 B per lane; LDS dest is wave-uniform base + lane*16
__device__ __forceinline__ void gld_lds16(const ushort* g, ushort* l) {
  __builtin_amdgcn_global_load_lds(
      (const __attribute__((address_space(1))) unsigned int*)g,
      (__attribute__((address_space(3))) unsigned int*)l, 16, 0, 0);
}

// ---------------- Kernel 0: weight transpose f32 -> bf16 ----------------
__global__ __launch_bounds__(256) void wt_kernel(
    const float* __restrict__ wq, const float* __restrict__ wk,
    const float* __restrict__ wv, const float* __restrict__ wg,
    const float* __restrict__ wo, ushort* __restrict__ Wt5) {
  __shared__ float t[64][65];
  int z = blockIdx.z;
  const float* W = (z == 0) ? wq : (z == 1) ? wk : (z == 2) ? wv
                   : (z == 3) ? wg : wo;
  ushort* Wt = Wt5 + (size_t)z * 65536;
  int tid = threadIdx.x;
  int r = tid >> 2, c4 = (tid & 3) * 16;
  int rowBase = blockIdx.y * 64, colBase = blockIdx.x * 64;
#pragma unroll
  for (int j = 0; j < 16; ++j)
    t[r][c4 + j] = W[(size_t)(rowBase + r) * 256 + colBase + c4 + j];
  __syncthreads();
#pragma unroll
  for (int j = 0; j < 16; ++j)
    Wt[(size_t)(colBase + r) * 256 + rowBase + c4 + j] = f2b(t[c4 + j][r]);
}

// ------- Kernel 1: LayerNorm of msa -> m (bf16), wave per row ----------
__global__ __launch_bounds__(256) void ln_msa_kernel(
    const float* __restrict__ x, const float* __restrict__ g,
    const float* __restrict__ b, ushort* __restrict__ m) {
  int lane = threadIdx.x & 63, w = threadIdx.x >> 6;
  int row = blockIdx.x * 4 + w;
  const float* xp = x + (size_t)row * CM + lane * 4;
  float4 v = *(const float4*)xp;
  float s1 = v.x + v.y + v.z + v.w;
  float s2 = v.x * v.x + v.y * v.y + v.z * v.z + v.w * v.w;
#pragma unroll
  for (int off = 32; off; off >>= 1) {
    s1 += __shfl_xor(s1, off, 64);
    s2 += __shfl_xor(s2, off, 64);
  }
  float mean = s1 * (1.0f / CM);
  float rstd = rsqrtf(s2 * (1.0f / CM) - mean * mean + 1e-5f);
  float4 gv = *(const float4*)(g + lane * 4);
  float4 bv = *(const float4*)(b + lane * 4);
  ushort4 o;
  o.x = f2b((v.x - mean) * rstd * gv.x + bv.x);
  o.y = f2b((v.y - mean) * rstd * gv.y + bv.y);
  o.z = f2b((v.z - mean) * rstd * gv.z + bv.z);
  o.w = f2b((v.w - mean) * rstd * gv.w + bv.w);
  *(ushort4*)(m + (size_t)row * CM + lane * 4) = o;
}

// ----- Kernel 2: pair LN + bias, 4 lanes per (i,j) row, in-register ----
__global__ __launch_bounds__(256) void pair_bias_kernel(
    const float* __restrict__ z, const float* __restrict__ g,
    const float* __restrict__ b, const float* __restrict__ w_b,
    const float* __restrict__ b_b, float* __restrict__ bias) {
  __shared__ float wbs[CZ][8];
  __shared__ float gs[CZ], bs[CZ];
  int tid = threadIdx.x;
  if (tid < CZ) { gs[tid] = g[tid]; bs[tid] = b[tid]; }
  for (int i = tid; i < CZ * 8; i += 256) wbs[i >> 3][i & 7] = w_b[i];
  __syncthreads();
  int q = tid & 3;
  int row = blockIdx.x * 64 + (tid >> 2);
  const float* zp = z + (size_t)row * CZ + q * 32;
  float4 v[8];
#pragma unroll
  for (int j = 0; j < 8; ++j) v[j] = *(const float4*)(zp + j * 4);
  float s1 = 0.f, s2 = 0.f;
#pragma unroll
  for (int j = 0; j < 8; ++j) {
    s1 += v[j].x + v[j].y + v[j].z + v[j].w;
    s2 += v[j].x * v[j].x + v[j].y * v[j].y + v[j].z * v[j].z +
          v[j].w * v[j].w;
  }
  s1 += __shfl_xor(s1, 1, 64);
  s2 += __shfl_xor(s2, 1, 64);
  s1 += __shfl_xor(s1, 2, 64);
  s2 += __shfl_xor(s2, 2, 64);
  float mean = s1 * (1.0f / CZ);
  float var = s2 * (1.0f / CZ) - mean * mean;
  float rstd = rsqrtf(var + 1e-5f);
  float acc[8] = {};
#pragma unroll
  for (int j = 0; j < 8; ++j) {
    float e[4] = {v[j].x, v[j].y, v[j].z, v[j].w};
#pragma unroll
    for (int u = 0; u < 4; ++u) {
      int c = q * 32 + j * 4 + u;
      float zn = (e[u] - mean) * rstd * gs[c] + bs[c];
#pragma unroll
      for (int h = 0; h < 8; ++h) acc[h] += zn * wbs[c][h];
    }
  }
#pragma unroll
  for (int h = 0; h < 8; ++h) {
    acc[h] += __shfl_xor(acc[h], 1, 64);
    acc[h] += __shfl_xor(acc[h], 2, 64);
  }
  int h0 = q * 2;
  bias[(size_t)h0 * (R_DIM * R_DIM) + row] = acc[h0] + b_b[h0];
  bias[(size_t)(h0 + 1) * (R_DIM * R_DIM) + row] = acc[h0 + 1] + b_b[h0 + 1];
}

// ---- Kernel 3: fused projection GEMM, 128x64 tile for occupancy -------
__global__ __launch_bounds__(256) void proj_mfma(
    const ushort* __restrict__ M, const ushort* __restrict__ Wt5,
    const float* __restrict__ b_g, ushort* __restrict__ qb,
    ushort* __restrict__ kb2, ushort* __restrict__ vb,
    ushort* __restrict__ gb) {
  __shared__ ushort As[128 * 64];
  __shared__ ushort Bs[64 * 64];
  int tid = threadIdx.x, lane = tid & 63, wid = tid >> 6;
  int lr = lane & 15, lg = lane >> 4;
  int rowBase = blockIdx.x * 128;
  int cby = blockIdx.y;             // 0..15; 64 fused cols each
  int proj = cby >> 2;
  int sc = (lane & 7) ^ ((lane >> 3) & 7);   // swizzled source chunk
  const ushort* Ag =
      M + (size_t)(rowBase + wid * 32 + (lane >> 3)) * 256 + sc * 8;
  const ushort* Bg =
      Wt5 + (size_t)(cby * 64 + wid * 16 + (lane >> 3)) * 256 + sc * 8;
  ushort* Asl = As + wid * (32 * 64);
  ushort* Bsl = Bs + wid * (16 * 64);
  int wr = wid >> 1, wc = wid & 1;
  int sx = (lr & 7) * 8;                      // read-side XOR (in ushorts)
  f32x4 zf = {0.f, 0.f, 0.f, 0.f};
  f32x4 acc[4][2];
#pragma unroll
  for (int i = 0; i < 4; ++i)
#pragma unroll
    for (int j = 0; j < 2; ++j) acc[i][j] = zf;

  for (int kb = 0; kb < 4; ++kb) {
    if (kb) __syncthreads();
#pragma unroll
    for (int c = 0; c < 4; ++c)
      gld_lds16(Ag + kb * 64 + c * (8 * 256), Asl + c * (8 * 64));
#pragma unroll
    for (int c = 0; c < 2; ++c)
      gld_lds16(Bg + kb * 64 + c * (8 * 256), Bsl + c * (8 * 64));
    __syncthreads();
#pragma unroll
    for (int kk = 0; kk < 2; ++kk) {
      bf16x8 a[4], b[2];
#pragma unroll
      for (int mf = 0; mf < 4; ++mf)
        a[mf] = *(const bf16x8*)&As[(wr * 64 + mf * 16 + lr) * 64 +
                                    ((kk * 32 + lg * 8) ^ sx)];
#pragma unroll
      for (int nf = 0; nf < 2; ++nf)
        b[nf] = *(const bf16x8*)&Bs[(wc * 32 + nf * 16 + lr) * 64 +
                                    ((kk * 32 + lg * 8) ^ sx)];
#pragma unroll
      for (int mf = 0; mf < 4; ++mf)
#pragma unroll
        for (int nf = 0; nf < 2; ++nf)
          acc[mf][nf] = __builtin_amdgcn_mfma_f32_16x16x32_bf16(
              b[nf], a[mf], acc[mf][nf], 0, 0, 0);   // swapped: C^T
    }
  }
  // epilogue: lane row = rowBase+wr*64+mf*16+lr; 4 consecutive cols
#pragma unroll
  for (int mf = 0; mf < 4; ++mf) {
    int row = rowBase + wr * 64 + mf * 16 + lr;
    int s = row >> 8, rr = row & 255;
#pragma unroll
    for (int nf = 0; nf < 2; ++nf) {
      int colL = (cby & 3) * 64 + wc * 32 + nf * 16 + lg * 4;
      int h = colL >> 5, d0 = colL & 31;
      size_t oidx = ((size_t)((s * H_DIM + h) * R_DIM + rr)) * C_DIM + d0;
      f32x4 v4 = acc[mf][nf];
      ushort4 o4;
      if (proj == 0) {
        o4.x = f2b(v4[0] * 0.17677669529663687f);
        o4.y = f2b(v4[1] * 0.17677669529663687f);
        o4.z = f2b(v4[2] * 0.17677669529663687f);
        o4.w = f2b(v4[3] * 0.17677669529663687f);
        *(ushort4*)(qb + oidx) = o4;
      } else if (proj == 1) {
        o4.x = f2b(v4[0]); o4.y = f2b(v4[1]);
        o4.z = f2b(v4[2]); o4.w = f2b(v4[3]);
        *(ushort4*)(kb2 + oidx) = o4;
      } else if (proj == 2) {
        o4.x = f2b(v4[0]); o4.y = f2b(v4[1]);
        o4.z = f2b(v4[2]); o4.w = f2b(v4[3]);
        *(ushort4*)(vb + oidx) = o4;
      } else {
        float4 bg4 = *(const float4*)(b_g + colL);
        o4.x = f2b(1.f / (1.f + __expf(-(v4[0] + bg4.x))));
        o4.y = f2b(1.f / (1.f + __expf(-(v4[1] + bg4.y))));
        o4.z = f2b(1.f / (1.f + __expf(-(v4[2] + bg4.z))));
        o4.w = f2b(1.f / (1.f + __expf(-(v4[3] + bg4.w))));
        *(ushort4*)(gb + oidx) = o4;
      }
    }
  }
}

// --- Kernel 4: MFMA flash attention per (s,h), 8 waves x 32 q rows ------
// R10 structure + next-tile K register prefetch (issue-early) + setprio.
__global__ __launch_bounds__(512, 4) void attn_mfma(
    const ushort* __restrict__ q, const ushort* __restrict__ k,
    const ushort* __restrict__ v, const ushort* __restrict__ g,
    const float* __restrict__ bias, ushort* __restrict__ ob) {
  __shared__ ushort Vt[32][264];     // V transposed [d][key]
  __shared__ ushort Pl[8][32][72];   // per-wave P tile [q][key]
  int blk = blockIdx.x;
  int s = blk >> 3, h = blk & 7;
  int tid = threadIdx.x, lane = tid & 63, w = tid >> 6;
  int lr = lane & 15, lg = lane >> 4;
  size_t base = (size_t)(s * H_DIM + h) * (R_DIM * C_DIM);

  // stage V transposed: 512 threads, each half a key row (16 d)
  {
    int key = tid >> 1, half = (tid & 1) * 16;
    const ushort* vp = v + base + (size_t)key * 32 + half;
    bf16x8 t0 = *(const bf16x8*)vp;
    bf16x8 t1 = *(const bf16x8*)(vp + 8);
#pragma unroll
    for (int j = 0; j < 8; ++j) {
      Vt[half + j][key] = (ushort)t0[j];
      Vt[half + 8 + j][key] = (ushort)t1[j];
    }
  }
  __syncthreads();

  int qrow0 = w * 32;
  bf16x8 qf[2];
#pragma unroll
  for (int mf = 0; mf < 2; ++mf)
    qf[mf] = *(const bf16x8*)(q + base + (size_t)(qrow0 + mf * 16 + lr) * 32 +
                              lg * 8);
  const float* bp0 = bias + ((size_t)h * R_DIM + qrow0 + lg * 4) * R_DIM +
                     lr * 4;

  float lsum[2][4] = {};
  f32x4 of[2][2];
  f32x4 zf = {0.f, 0.f, 0.f, 0.f};
#pragma unroll
  for (int mf = 0; mf < 2; ++mf) {
    of[mf][0] = zf;
    of[mf][1] = zf;
  }

  // prefetch K fragments for t=0
  bf16x8 kf[4];
#pragma unroll
  for (int nf = 0; nf < 4; ++nf)
    kf[nf] = *(const bf16x8*)(k + base + (size_t)(lr * 4 + nf) * 32 + lg * 8);

#pragma unroll
  for (int t = 0; t < 4; ++t) {
    int k0 = t * 64;
    // issue next tile's K loads BEFORE compute (hide HBM under QK+SM+PV)
    bf16x8 kfn[4];
    if (t < 3) {
#pragma unroll
      for (int nf = 0; nf < 4; ++nf)
        kfn[nf] = *(const bf16x8*)(k + base +
                                   (size_t)(k0 + 64 + lr * 4 + nf) * 32 +
                                   lg * 8);
    }
    f32x4 sf[2][4];
    __builtin_amdgcn_s_setprio(1);
#pragma unroll
    for (int mf = 0; mf < 2; ++mf)
#pragma unroll
      for (int nf = 0; nf < 4; ++nf)
        sf[mf][nf] =
            __builtin_amdgcn_mfma_f32_16x16x32_bf16(qf[mf], kf[nf], zf, 0, 0, 0);
    __builtin_amdgcn_s_setprio(0);
#pragma unroll
    for (int mf = 0; mf < 2; ++mf) {
      float4 bv[4];
#pragma unroll
      for (int r = 0; r < 4; ++r)
        bv[r] = *(const float4*)(bp0 + (size_t)(mf * 16 + r) * R_DIM + k0);
#pragma unroll
      for (int r = 0; r < 4; ++r) {
        float p0 = __expf(sf[mf][0][r] + bv[r].x);
        float p1 = __expf(sf[mf][1][r] + bv[r].y);
        float p2 = __expf(sf[mf][2][r] + bv[r].z);
        float p3 = __expf(sf[mf][3][r] + bv[r].w);
        lsum[mf][r] += (p0 + p1) + (p2 + p3);
        ushort4 pk;
        pk.x = f2b(p0);
        pk.y = f2b(p1);
        pk.z = f2b(p2);
        pk.w = f2b(p3);
        *(ushort4*)&Pl[w][mf * 16 + lg * 4 + r][lr * 4] = pk;
      }
    }
    // PV swapped: of[mf][df] rows = q (lr), d = lg*4+r (consecutive)
    __builtin_amdgcn_s_setprio(1);
#pragma unroll
    for (int kt = 0; kt < 2; ++kt) {
      bf16x8 pf[2], vf[2];
#pragma unroll
      for (int mf = 0; mf < 2; ++mf)
        pf[mf] = *(const bf16x8*)&Pl[w][mf * 16 + lr][kt * 32 + lg * 8];
#pragma unroll
      for (int df = 0; df < 2; ++df)
        vf[df] = *(const bf16x8*)&Vt[df * 16 + lr][k0 + kt * 32 + lg * 8];
#pragma unroll
      for (int mf = 0; mf < 2; ++mf)
#pragma unroll
        for (int df = 0; df < 2; ++df)
          of[mf][df] = __builtin_amdgcn_mfma_f32_16x16x32_bf16(
              vf[df], pf[mf], of[mf][df], 0, 0, 0);
    }
    __builtin_amdgcn_s_setprio(0);
    if (t < 3) {
#pragma unroll
      for (int nf = 0; nf < 4; ++nf) kf[nf] = kfn[nf];
    }
  }
  // lsum ladder (uniform over lr), then gather per of-row (= mf*16+lr)
#pragma unroll
  for (int mf = 0; mf < 2; ++mf)
#pragma unroll
    for (int r = 0; r < 4; ++r) {
#pragma unroll
      for (int msk = 1; msk <= 8; msk <<= 1)
        lsum[mf][r] += __shfl_xor(lsum[mf][r], msk, 64);
    }
  int srcl = ((lr >> 2) << 4) + lr;
  float invr[2];
#pragma unroll
  for (int mf = 0; mf < 2; ++mf) {
    float t0 = __shfl(lsum[mf][0], srcl, 64);
    float t1 = __shfl(lsum[mf][1], srcl, 64);
    float t2 = __shfl(lsum[mf][2], srcl, 64);
    float t3 = __shfl(lsum[mf][3], srcl, 64);
    int rb = lr & 3;
    float lv = rb == 0 ? t0 : rb == 1 ? t1 : rb == 2 ? t2 : t3;
    invr[mf] = 1.f / lv;
  }
  // epilogue: vectorized gate+store (ushort4)
#pragma unroll
  for (int mf = 0; mf < 2; ++mf) {
    int row = qrow0 + mf * 16 + lr;
#pragma unroll
    for (int df = 0; df < 2; ++df) {
      int d0 = df * 16 + lg * 4;
      ushort4 g4 = *(const ushort4*)(g + base + (size_t)row * 32 + d0);
      ushort4 o4;
      o4.x = f2b(of[mf][df][0] * invr[mf] * b2f(g4.x));
      o4.y = f2b(of[mf][df][1] * invr[mf] * b2f(g4.y));
      o4.z = f2b(of[mf][df][2] * invr[mf] * b2f(g4.z));
      o4.w = f2b(of[mf][df][3] * invr[mf] * b2f(g4.w));
      *(ushort4*)(ob + ((size_t)(s * R_DIM + row)) * 256 + h * 32 + d0) = o4;
    }
  }
}

// ---- Kernel 5: output GEMM, 128x64 tile for occupancy -----------------
__global__ __launch_bounds__(256) void out_mfma(
    const ushort* __restrict__ A, const ushort* __restrict__ Wt,
    const float* __restrict__ b_o, float* __restrict__ out) {
  __shared__ ushort As[128 * 64];
  __shared__ ushort Bs[64 * 64];
  int tid = threadIdx.x, lane = tid & 63, wid = tid >> 6;
  int lr = lane & 15, lg = lane >> 4;
  int rowBase = blockIdx.x * 128;
  int colBase = blockIdx.y * 64;
  int sc = (lane & 7) ^ ((lane >> 3) & 7);
  const ushort* Ag =
      A + (size_t)(rowBase + wid * 32 + (lane >> 3)) * 256 + sc * 8;
  const ushort* Bg =
      Wt + (size_t)(colBase + wid * 16 + (lane >> 3)) * 256 + sc * 8;
  ushort* Asl = As + wid * (32 * 64);
  ushort* Bsl = Bs + wid * (16 * 64);
  int wr = wid >> 1, wc = wid & 1;
  int sx = (lr & 7) * 8;
  f32x4 zf = {0.f, 0.f, 0.f, 0.f};
  f32x4 acc[4][2];
#pragma unroll
  for (int i = 0; i < 4; ++i)
#pragma unroll
    for (int j = 0; j < 2; ++j) acc[i][j] = zf;

  for (int kb = 0; kb < 4; ++kb) {
    if (kb) __syncthreads();
#pragma unroll
    for (int c = 0; c < 4; ++c)
      gld_lds16(Ag + kb * 64 + c * (8 * 256), Asl + c * (8 * 64));
#pragma unroll
    for (int c = 0; c < 2; ++c)
      gld_lds16(Bg + kb * 64 + c * (8 * 256), Bsl + c * (8 * 64));
    __syncthreads();
#pragma unroll
    for (int kk = 0; kk < 2; ++kk) {
      bf16x8 a[4], b[2];
#pragma unroll
      for (int mf = 0; mf < 4; ++mf)
        a[mf] = *(const bf16x8*)&As[(wr * 64 + mf * 16 + lr) * 64 +
                                    ((kk * 32 + lg * 8) ^ sx)];
#pragma unroll
      for (int nf = 0; nf < 2; ++nf)
        b[nf] = *(const bf16x8*)&Bs[(wc * 32 + nf * 16 + lr) * 64 +
                                    ((kk * 32 + lg * 8) ^ sx)];
#pragma unroll
      for (int mf = 0; mf < 4; ++mf)
#pragma unroll
        for (int nf = 0; nf < 2; ++nf)
          acc[mf][nf] = __builtin_amdgcn_mfma_f32_16x16x32_bf16(
              b[nf], a[mf], acc[mf][nf], 0, 0, 0);   // swapped: C^T
    }
  }
#pragma unroll
  for (int mf = 0; mf < 4; ++mf) {
    int row = rowBase + wr * 64 + mf * 16 + lr;
#pragma unroll
    for (int nf = 0; nf < 2; ++nf) {
      int col0 = colBase + wc * 32 + nf * 16 + lg * 4;
      float4 bo4 = *(const float4*)(b_o + col0);
      float4 o4;
      o4.x = acc[mf][nf][0] + bo4.x;
      o4.y = acc[mf][nf][1] + bo4.y;
      o4.z = acc[mf][nf][2] + bo4.z;
      o4.w = acc[mf][nf][3] + bo4.w;
      *(float4*)(out + (size_t)row * 256 + col0) = o4;
    }
  }
}

extern "C" void kernel_launch(void* const* d_in, const int* in_sizes, int n_in,
                              void* d_out, int out_size, void* d_ws,
                              size_t ws_size, hipStream_t stream) {
  const float* msa      = (const float*)d_in[0];
  const float* pair     = (const float*)d_in[1];
  const float* ln_msa_g = (const float*)d_in[2];
  const float* ln_msa_b = (const float*)d_in[3];
  const float* ln_pr_g  = (const float*)d_in[4];
  const float* ln_pr_b  = (const float*)d_in[5];
  const float* w_q      = (const float*)d_in[6];
  const float* w_k      = (const float*)d_in[7];
  const float* w_v      = (const float*)d_in[8];
  const float* w_g      = (const float*)d_in[9];
  const float* b_g      = (const float*)d_in[10];
  const float* w_b      = (const float*)d_in[11];
  const float* b_b      = (const float*)d_in[12];
  const float* w_o      = (const float*)d_in[13];
  const float* b_o      = (const float*)d_in[14];
  float* out = (float*)d_out;

  char* ws = (char*)d_ws;
  ushort* m   = (ushort*)(ws + 0);            // 16,777,216
  ushort* qb  = (ushort*)(ws + 16777216ull);  // 16,777,216
  ushort* kb  = (ushort*)(ws + 33554432ull);  // 16,777,216
  ushort* vb  = (ushort*)(ws + 50331648ull);  // 16,777,216
  ushort* gb  = (ushort*)(ws + 67108864ull);  // 16,777,216
  float*  bi  = (float*) (ws + 83886080ull);  //  2,097,152
  ushort* ob  = (ushort*)(ws + 85983232ull);  // 16,777,216
  ushort* Wt5 = (ushort*)(ws + 102760448ull); //    655,360

  wt_kernel<<<dim3(4, 4, 5), 256, 0, stream>>>(w_q, w_k, w_v, w_g, w_o, Wt5);
  ln_msa_kernel<<<S_DIM * R_DIM / 4, 256, 0, stream>>>(msa, ln_msa_g,
                                                       ln_msa_b, m);
  pair_bias_kernel<<<R_DIM * R_DIM / 64, 256, 0, stream>>>(
      pair, ln_pr_g, ln_pr_b, w_b, b_b, bi);
  proj_mfma<<<dim3(256, 16), 256, 0, stream>>>(m, Wt5, b_g, qb, kb, vb, gb);
  attn_mfma<<<S_DIM * H_DIM, 512, 0, stream>>>(qb, kb, vb, gb, bi, ob);
  out_mfma<<<dim3(256, 4), 256, 0, stream>>>(ob, Wt5 + 4 * 65536, b_o, out);
}

// Round 13
// 112.861 us; speedup vs baseline: 1.5191x; 1.0412x over previous
//
#include <hip/hip_runtime.h>
#include <hip/hip_bf16.h>

#define S_DIM 128
#define R_DIM 256
#define CM 256
#define CZ 128
#define H_DIM 8
#define C_DIM 32

typedef short bf16x8 __attribute__((ext_vector_type(8)));
typedef float f32x4 __attribute__((ext_vector_type(4)));

__device__ inline ushort f2b(float f) {
  __hip_bfloat16 b = __float2bfloat16(f);
  return *(ushort*)&b;
}
__device__ inline float b2f(ushort u) {
  __hip_bfloat16 b = *(__hip_bfloat16*)&u;
  return __bfloat162float(b);
}

// async global->LDS, 16 B per lane; LDS dest is wave-uniform base + lane*16
__device__ __forceinline__ void gld_lds16(const ushort* g, ushort* l) {
  __builtin_amdgcn_global_load_lds(
      (const __attribute__((address_space(1))) unsigned int*)g,
      (__attribute__((address_space(3))) unsigned int*)l, 16, 0, 0);
}

// ---- Kernel A: fused prologue (ln_msa | pair_bias | wt), branch on blk ----
// blocks [0,8192): ln_msa; [8192,9216): pair_bias; [9216,9296): wt
__global__ __launch_bounds__(256) void prologue_kernel(
    const float* __restrict__ msa, const float* __restrict__ ln_msa_g,
    const float* __restrict__ ln_msa_b, ushort* __restrict__ m,
    const float* __restrict__ pair, const float* __restrict__ ln_pr_g,
    const float* __restrict__ ln_pr_b, const float* __restrict__ w_b,
    const float* __restrict__ b_b, float* __restrict__ bias,
    const float* __restrict__ wq, const float* __restrict__ wk,
    const float* __restrict__ wv, const float* __restrict__ wg,
    const float* __restrict__ wo, ushort* __restrict__ Wt5) {
  __shared__ float t[64][65];
  __shared__ float wbs[CZ][8];
  __shared__ float gs[CZ], bs[CZ];
  int b = blockIdx.x;
  int tid = threadIdx.x;
  if (b < 8192) {
    // ---------------- LayerNorm msa, wave per row ----------------
    int lane = tid & 63, w = tid >> 6;
    int row = b * 4 + w;
    const float* xp = msa + (size_t)row * CM + lane * 4;
    float4 v = *(const float4*)xp;
    float s1 = v.x + v.y + v.z + v.w;
    float s2 = v.x * v.x + v.y * v.y + v.z * v.z + v.w * v.w;
#pragma unroll
    for (int off = 32; off; off >>= 1) {
      s1 += __shfl_xor(s1, off, 64);
      s2 += __shfl_xor(s2, off, 64);
    }
    float mean = s1 * (1.0f / CM);
    float rstd = rsqrtf(s2 * (1.0f / CM) - mean * mean + 1e-5f);
    float4 gv = *(const float4*)(ln_msa_g + lane * 4);
    float4 bv = *(const float4*)(ln_msa_b + lane * 4);
    ushort4 o;
    o.x = f2b((v.x - mean) * rstd * gv.x + bv.x);
    o.y = f2b((v.y - mean) * rstd * gv.y + bv.y);
    o.z = f2b((v.z - mean) * rstd * gv.z + bv.z);
    o.w = f2b((v.w - mean) * rstd * gv.w + bv.w);
    *(ushort4*)(m + (size_t)row * CM + lane * 4) = o;
  } else if (b < 9216) {
    // ---------------- pair LN + bias, 4 lanes per row ----------------
    int bb = b - 8192;
    if (tid < CZ) { gs[tid] = ln_pr_g[tid]; bs[tid] = ln_pr_b[tid]; }
    for (int i = tid; i < CZ * 8; i += 256) wbs[i >> 3][i & 7] = w_b[i];
    __syncthreads();
    int q = tid & 3;
    int row = bb * 64 + (tid >> 2);
    const float* zp = pair + (size_t)row * CZ + q * 32;
    float4 v[8];
#pragma unroll
    for (int j = 0; j < 8; ++j) v[j] = *(const float4*)(zp + j * 4);
    float s1 = 0.f, s2 = 0.f;
#pragma unroll
    for (int j = 0; j < 8; ++j) {
      s1 += v[j].x + v[j].y + v[j].z + v[j].w;
      s2 += v[j].x * v[j].x + v[j].y * v[j].y + v[j].z * v[j].z +
            v[j].w * v[j].w;
    }
    s1 += __shfl_xor(s1, 1, 64);
    s2 += __shfl_xor(s2, 1, 64);
    s1 += __shfl_xor(s1, 2, 64);
    s2 += __shfl_xor(s2, 2, 64);
    float mean = s1 * (1.0f / CZ);
    float var = s2 * (1.0f / CZ) - mean * mean;
    float rstd = rsqrtf(var + 1e-5f);
    float acc[8] = {};
#pragma unroll
    for (int j = 0; j < 8; ++j) {
      float e[4] = {v[j].x, v[j].y, v[j].z, v[j].w};
#pragma unroll
      for (int u = 0; u < 4; ++u) {
        int c = q * 32 + j * 4 + u;
        float zn = (e[u] - mean) * rstd * gs[c] + bs[c];
#pragma unroll
        for (int h = 0; h < 8; ++h) acc[h] += zn * wbs[c][h];
      }
    }
#pragma unroll
    for (int h = 0; h < 8; ++h) {
      acc[h] += __shfl_xor(acc[h], 1, 64);
      acc[h] += __shfl_xor(acc[h], 2, 64);
    }
    int h0 = q * 2;
    bias[(size_t)h0 * (R_DIM * R_DIM) + row] = acc[h0] + b_b[h0];
    bias[(size_t)(h0 + 1) * (R_DIM * R_DIM) + row] = acc[h0 + 1] + b_b[h0 + 1];
  } else {
    // ---------------- weight transpose f32 -> bf16 ----------------
    int zz = b - 9216;                 // 0..79
    int z = zz >> 4, rem = zz & 15;
    int by = rem >> 2, bx = rem & 3;
    const float* W = (z == 0) ? wq : (z == 1) ? wk : (z == 2) ? wv
                     : (z == 3) ? wg : wo;
    ushort* Wt = Wt5 + (size_t)z * 65536;
    int r = tid >> 2, c4 = (tid & 3) * 16;
    int rowBase = by * 64, colBase = bx * 64;
#pragma unroll
    for (int j = 0; j < 16; ++j)
      t[r][c4 + j] = W[(size_t)(rowBase + r) * 256 + colBase + c4 + j];
    __syncthreads();
#pragma unroll
    for (int j = 0; j < 16; ++j)
      Wt[(size_t)(colBase + r) * 256 + rowBase + c4 + j] = f2b(t[c4 + j][r]);
  }
}

// ---- Kernel 3: fused projection GEMM, 128x128 block (2 col-tiles/A-stage)
__global__ __launch_bounds__(256) void proj_mfma(
    const ushort* __restrict__ M, const ushort* __restrict__ Wt5,
    const float* __restrict__ b_g, ushort* __restrict__ qb,
    ushort* __restrict__ kb2, ushort* __restrict__ vb,
    ushort* __restrict__ gb) {
  __shared__ ushort As[128 * 64];
  __shared__ ushort Bs[2][64 * 64];
  int tid = threadIdx.x, lane = tid & 63, wid = tid >> 6;
  int lr = lane & 15, lg = lane >> 4;
  int rowBase = blockIdx.x * 128;
  int cby = blockIdx.y;             // 0..7; 128 fused cols each
  int proj = cby >> 1;
  int sc = (lane & 7) ^ ((lane >> 3) & 7);   // swizzled source chunk
  const ushort* Ag =
      M + (size_t)(rowBase + wid * 32 + (lane >> 3)) * 256 + sc * 8;
  const ushort* Bg0 =
      Wt5 + (size_t)(cby * 128 + wid * 16 + (lane >> 3)) * 256 + sc * 8;
  const ushort* Bg1 = Bg0 + (size_t)64 * 256;
  ushort* Asl = As + wid * (32 * 64);
  ushort* Bsl0 = Bs[0] + wid * (16 * 64);
  ushort* Bsl1 = Bs[1] + wid * (16 * 64);
  int wr = wid >> 1, wc = wid & 1;
  int sx = (lr & 7) * 8;                      // read-side XOR (in ushorts)
  f32x4 zf = {0.f, 0.f, 0.f, 0.f};
  f32x4 acc[2][4][2];
#pragma unroll
  for (int c = 0; c < 2; ++c)
#pragma unroll
    for (int i = 0; i < 4; ++i)
#pragma unroll
      for (int j = 0; j < 2; ++j) acc[c][i][j] = zf;

  for (int kb = 0; kb < 4; ++kb) {
    if (kb) __syncthreads();
#pragma unroll
    for (int c = 0; c < 4; ++c)
      gld_lds16(Ag + kb * 64 + c * (8 * 256), Asl + c * (8 * 64));
#pragma unroll
    for (int c = 0; c < 2; ++c) {
      gld_lds16(Bg0 + kb * 64 + c * (8 * 256), Bsl0 + c * (8 * 64));
      gld_lds16(Bg1 + kb * 64 + c * (8 * 256), Bsl1 + c * (8 * 64));
    }
    __syncthreads();
#pragma unroll
    for (int kk = 0; kk < 2; ++kk) {
      bf16x8 a[4], b0[2], b1[2];
#pragma unroll
      for (int mf = 0; mf < 4; ++mf)
        a[mf] = *(const bf16x8*)&As[(wr * 64 + mf * 16 + lr) * 64 +
                                    ((kk * 32 + lg * 8) ^ sx)];
#pragma unroll
      for (int nf = 0; nf < 2; ++nf) {
        b0[nf] = *(const bf16x8*)&Bs[0][(wc * 32 + nf * 16 + lr) * 64 +
                                        ((kk * 32 + lg * 8) ^ sx)];
        b1[nf] = *(const bf16x8*)&Bs[1][(wc * 32 + nf * 16 + lr) * 64 +
                                        ((kk * 32 + lg * 8) ^ sx)];
      }
#pragma unroll
      for (int mf = 0; mf < 4; ++mf)
#pragma unroll
        for (int nf = 0; nf < 2; ++nf) {
          acc[0][mf][nf] = __builtin_amdgcn_mfma_f32_16x16x32_bf16(
              b0[nf], a[mf], acc[0][mf][nf], 0, 0, 0);   // swapped: C^T
          acc[1][mf][nf] = __builtin_amdgcn_mfma_f32_16x16x32_bf16(
              b1[nf], a[mf], acc[1][mf][nf], 0, 0, 0);
        }
    }
  }
  // epilogue: lane row = rowBase+wr*64+mf*16+lr; 4 consecutive cols
#pragma unroll
  for (int cc = 0; cc < 2; ++cc)
#pragma unroll
    for (int mf = 0; mf < 4; ++mf) {
      int row = rowBase + wr * 64 + mf * 16 + lr;
      int s = row >> 8, rr = row & 255;
#pragma unroll
      for (int nf = 0; nf < 2; ++nf) {
        int colL = (cby & 1) * 128 + cc * 64 + wc * 32 + nf * 16 + lg * 4;
        int h = colL >> 5, d0 = colL & 31;
        size_t oidx = ((size_t)((s * H_DIM + h) * R_DIM + rr)) * C_DIM + d0;
        f32x4 v4 = acc[cc][mf][nf];
        ushort4 o4;
        if (proj == 0) {
          o4.x = f2b(v4[0] * 0.17677669529663687f);
          o4.y = f2b(v4[1] * 0.17677669529663687f);
          o4.z = f2b(v4[2] * 0.17677669529663687f);
          o4.w = f2b(v4[3] * 0.17677669529663687f);
          *(ushort4*)(qb + oidx) = o4;
        } else if (proj == 1) {
          o4.x = f2b(v4[0]); o4.y = f2b(v4[1]);
          o4.z = f2b(v4[2]); o4.w = f2b(v4[3]);
          *(ushort4*)(kb2 + oidx) = o4;
        } else if (proj == 2) {
          o4.x = f2b(v4[0]); o4.y = f2b(v4[1]);
          o4.z = f2b(v4[2]); o4.w = f2b(v4[3]);
          *(ushort4*)(vb + oidx) = o4;
        } else {
          float4 bg4 = *(const float4*)(b_g + colL);
          o4.x = f2b(1.f / (1.f + __expf(-(v4[0] + bg4.x))));
          o4.y = f2b(1.f / (1.f + __expf(-(v4[1] + bg4.y))));
          o4.z = f2b(1.f / (1.f + __expf(-(v4[2] + bg4.z))));
          o4.w = f2b(1.f / (1.f + __expf(-(v4[3] + bg4.w))));
          *(ushort4*)(gb + oidx) = o4;
        }
      }
    }
}

// --- Kernel 4: MFMA flash attention per (s,h), 8 waves x 32 q rows ------
// R10 structure + next-tile K register prefetch (issue-early) + setprio.
__global__ __launch_bounds__(512, 4) void attn_mfma(
    const ushort* __restrict__ q, const ushort* __restrict__ k,
    const ushort* __restrict__ v, const ushort* __restrict__ g,
    const float* __restrict__ bias, ushort* __restrict__ ob) {
  __shared__ ushort Vt[32][264];     // V transposed [d][key]
  __shared__ ushort Pl[8][32][72];   // per-wave P tile [q][key]
  int blk = blockIdx.x;
  int s = blk >> 3, h = blk & 7;
  int tid = threadIdx.x, lane = tid & 63, w = tid >> 6;
  int lr = lane & 15, lg = lane >> 4;
  size_t base = (size_t)(s * H_DIM + h) * (R_DIM * C_DIM);

  // stage V transposed: 512 threads, each half a key row (16 d)
  {
    int key = tid >> 1, half = (tid & 1) * 16;
    const ushort* vp = v + base + (size_t)key * 32 + half;
    bf16x8 t0 = *(const bf16x8*)vp;
    bf16x8 t1 = *(const bf16x8*)(vp + 8);
#pragma unroll
    for (int j = 0; j < 8; ++j) {
      Vt[half + j][key] = (ushort)t0[j];
      Vt[half + 8 + j][key] = (ushort)t1[j];
    }
  }
  __syncthreads();

  int qrow0 = w * 32;
  bf16x8 qf[2];
#pragma unroll
  for (int mf = 0; mf < 2; ++mf)
    qf[mf] = *(const bf16x8*)(q + base + (size_t)(qrow0 + mf * 16 + lr) * 32 +
                              lg * 8);
  const float* bp0 = bias + ((size_t)h * R_DIM + qrow0 + lg * 4) * R_DIM +
                     lr * 4;

  float lsum[2][4] = {};
  f32x4 of[2][2];
  f32x4 zf = {0.f, 0.f, 0.f, 0.f};
#pragma unroll
  for (int mf = 0; mf < 2; ++mf) {
    of[mf][0] = zf;
    of[mf][1] = zf;
  }

  // prefetch K fragments for t=0
  bf16x8 kf[4];
#pragma unroll
  for (int nf = 0; nf < 4; ++nf)
    kf[nf] = *(const bf16x8*)(k + base + (size_t)(lr * 4 + nf) * 32 + lg * 8);

#pragma unroll
  for (int t = 0; t < 4; ++t) {
    int k0 = t * 64;
    // issue next tile's K loads BEFORE compute (hide HBM under QK+SM+PV)
    bf16x8 kfn[4];
    if (t < 3) {
#pragma unroll
      for (int nf = 0; nf < 4; ++nf)
        kfn[nf] = *(const bf16x8*)(k + base +
                                   (size_t)(k0 + 64 + lr * 4 + nf) * 32 +
                                   lg * 8);
    }
    f32x4 sf[2][4];
    __builtin_amdgcn_s_setprio(1);
#pragma unroll
    for (int mf = 0; mf < 2; ++mf)
#pragma unroll
      for (int nf = 0; nf < 4; ++nf)
        sf[mf][nf] =
            __builtin_amdgcn_mfma_f32_16x16x32_bf16(qf[mf], kf[nf], zf, 0, 0, 0);
    __builtin_amdgcn_s_setprio(0);
#pragma unroll
    for (int mf = 0; mf < 2; ++mf) {
      float4 bv[4];
#pragma unroll
      for (int r = 0; r < 4; ++r)
        bv[r] = *(const float4*)(bp0 + (size_t)(mf * 16 + r) * R_DIM + k0);
#pragma unroll
      for (int r = 0; r < 4; ++r) {
        float p0 = __expf(sf[mf][0][r] + bv[r].x);
        float p1 = __expf(sf[mf][1][r] + bv[r].y);
        float p2 = __expf(sf[mf][2][r] + bv[r].z);
        float p3 = __expf(sf[mf][3][r] + bv[r].w);
        lsum[mf][r] += (p0 + p1) + (p2 + p3);
        ushort4 pk;
        pk.x = f2b(p0);
        pk.y = f2b(p1);
        pk.z = f2b(p2);
        pk.w = f2b(p3);
        *(ushort4*)&Pl[w][mf * 16 + lg * 4 + r][lr * 4] = pk;
      }
    }
    // PV swapped: of[mf][df] rows = q (lr), d = lg*4+r (consecutive)
    __builtin_amdgcn_s_setprio(1);
#pragma unroll
    for (int kt = 0; kt < 2; ++kt) {
      bf16x8 pf[2], vf[2];
#pragma unroll
      for (int mf = 0; mf < 2; ++mf)
        pf[mf] = *(const bf16x8*)&Pl[w][mf * 16 + lr][kt * 32 + lg * 8];
#pragma unroll
      for (int df = 0; df < 2; ++df)
        vf[df] = *(const bf16x8*)&Vt[df * 16 + lr][k0 + kt * 32 + lg * 8];
#pragma unroll
      for (int mf = 0; mf < 2; ++mf)
#pragma unroll
        for (int df = 0; df < 2; ++df)
          of[mf][df] = __builtin_amdgcn_mfma_f32_16x16x32_bf16(
              vf[df], pf[mf], of[mf][df], 0, 0, 0);
    }
    __builtin_amdgcn_s_setprio(0);
    if (t < 3) {
#pragma unroll
      for (int nf = 0; nf < 4; ++nf) kf[nf] = kfn[nf];
    }
  }
  // lsum ladder (uniform over lr), then gather per of-row (= mf*16+lr)
#pragma unroll
  for (int mf = 0; mf < 2; ++mf)
#pragma unroll
    for (int r = 0; r < 4; ++r) {
#pragma unroll
      for (int msk = 1; msk <= 8; msk <<= 1)
        lsum[mf][r] += __shfl_xor(lsum[mf][r], msk, 64);
    }
  int srcl = ((lr >> 2) << 4) + lr;
  float invr[2];
#pragma unroll
  for (int mf = 0; mf < 2; ++mf) {
    float t0 = __shfl(lsum[mf][0], srcl, 64);
    float t1 = __shfl(lsum[mf][1], srcl, 64);
    float t2 = __shfl(lsum[mf][2], srcl, 64);
    float t3 = __shfl(lsum[mf][3], srcl, 64);
    int rb = lr & 3;
    float lv = rb == 0 ? t0 : rb == 1 ? t1 : rb == 2 ? t2 : t3;
    invr[mf] = 1.f / lv;
  }
  // epilogue: vectorized gate+store (ushort4)
#pragma unroll
  for (int mf = 0; mf < 2; ++mf) {
    int row = qrow0 + mf * 16 + lr;
#pragma unroll
    for (int df = 0; df < 2; ++df) {
      int d0 = df * 16 + lg * 4;
      ushort4 g4 = *(const ushort4*)(g + base + (size_t)row * 32 + d0);
      ushort4 o4;
      o4.x = f2b(of[mf][df][0] * invr[mf] * b2f(g4.x));
      o4.y = f2b(of[mf][df][1] * invr[mf] * b2f(g4.y));
      o4.z = f2b(of[mf][df][2] * invr[mf] * b2f(g4.z));
      o4.w = f2b(of[mf][df][3] * invr[mf] * b2f(g4.w));
      *(ushort4*)(ob + ((size_t)(s * R_DIM + row)) * 256 + h * 32 + d0) = o4;
    }
  }
}

// ---- Kernel 5: output GEMM, 128x128 block (2 col-tiles/A-stage) -------
__global__ __launch_bounds__(256) void out_mfma(
    const ushort* __restrict__ A, const ushort* __restrict__ Wt,
    const float* __restrict__ b_o, float* __restrict__ out) {
  __shared__ ushort As[128 * 64];
  __shared__ ushort Bs[2][64 * 64];
  int tid = threadIdx.x, lane = tid & 63, wid = tid >> 6;
  int lr = lane & 15, lg = lane >> 4;
  int rowBase = blockIdx.x * 128;
  int cby = blockIdx.y;             // 0..1; 128 cols each
  int sc = (lane & 7) ^ ((lane >> 3) & 7);
  const ushort* Ag =
      A + (size_t)(rowBase + wid * 32 + (lane >> 3)) * 256 + sc * 8;
  const ushort* Bg0 =
      Wt + (size_t)(cby * 128 + wid * 16 + (lane >> 3)) * 256 + sc * 8;
  const ushort* Bg1 = Bg0 + (size_t)64 * 256;
  ushort* Asl = As + wid * (32 * 64);
  ushort* Bsl0 = Bs[0] + wid * (16 * 64);
  ushort* Bsl1 = Bs[1] + wid * (16 * 64);
  int wr = wid >> 1, wc = wid & 1;
  int sx = (lr & 7) * 8;
  f32x4 zf = {0.f, 0.f, 0.f, 0.f};
  f32x4 acc[2][4][2];
#pragma unroll
  for (int c = 0; c < 2; ++c)
#pragma unroll
    for (int i = 0; i < 4; ++i)
#pragma unroll
      for (int j = 0; j < 2; ++j) acc[c][i][j] = zf;

  for (int kb = 0; kb < 4; ++kb) {
    if (kb) __syncthreads();
#pragma unroll
    for (int c = 0; c < 4; ++c)
      gld_lds16(Ag + kb * 64 + c * (8 * 256), Asl + c * (8 * 64));
#pragma unroll
    for (int c = 0; c < 2; ++c) {
      gld_lds16(Bg0 + kb * 64 + c * (8 * 256), Bsl0 + c * (8 * 64));
      gld_lds16(Bg1 + kb * 64 + c * (8 * 256), Bsl1 + c * (8 * 64));
    }
    __syncthreads();
#pragma unroll
    for (int kk = 0; kk < 2; ++kk) {
      bf16x8 a[4], b0[2], b1[2];
#pragma unroll
      for (int mf = 0; mf < 4; ++mf)
        a[mf] = *(const bf16x8*)&As[(wr * 64 + mf * 16 + lr) * 64 +
                                    ((kk * 32 + lg * 8) ^ sx)];
#pragma unroll
      for (int nf = 0; nf < 2; ++nf) {
        b0[nf] = *(const bf16x8*)&Bs[0][(wc * 32 + nf * 16 + lr) * 64 +
                                        ((kk * 32 + lg * 8) ^ sx)];
        b1[nf] = *(const bf16x8*)&Bs[1][(wc * 32 + nf * 16 + lr) * 64 +
                                        ((kk * 32 + lg * 8) ^ sx)];
      }
#pragma unroll
      for (int mf = 0; mf < 4; ++mf)
#pragma unroll
        for (int nf = 0; nf < 2; ++nf) {
          acc[0][mf][nf] = __builtin_amdgcn_mfma_f32_16x16x32_bf16(
              b0[nf], a[mf], acc[0][mf][nf], 0, 0, 0);   // swapped: C^T
          acc[1][mf][nf] = __builtin_amdgcn_mfma_f32_16x16x32_bf16(
              b1[nf], a[mf], acc[1][mf][nf], 0, 0, 0);
        }
    }
  }
#pragma unroll
  for (int cc = 0; cc < 2; ++cc)
#pragma unroll
    for (int mf = 0; mf < 4; ++mf) {
      int row = rowBase + wr * 64 + mf * 16 + lr;
#pragma unroll
      for (int nf = 0; nf < 2; ++nf) {
        int col0 = cby * 128 + cc * 64 + wc * 32 + nf * 16 + lg * 4;
        float4 bo4 = *(const float4*)(b_o + col0);
        float4 o4;
        o4.x = acc[cc][mf][nf][0] + bo4.x;
        o4.y = acc[cc][mf][nf][1] + bo4.y;
        o4.z = acc[cc][mf][nf][2] + bo4.z;
        o4.w = acc[cc][mf][nf][3] + bo4.w;
        *(float4*)(out + (size_t)row * 256 + col0) = o4;
      }
    }
}

extern "C" void kernel_launch(void* const* d_in, const int* in_sizes, int n_in,
                              void* d_out, int out_size, void* d_ws,
                              size_t ws_size, hipStream_t stream) {
  const float* msa      = (const float*)d_in[0];
  const float* pair     = (const float*)d_in[1];
  const float* ln_msa_g = (const float*)d_in[2];
  const float* ln_msa_b = (const float*)d_in[3];
  const float* ln_pr_g  = (const float*)d_in[4];
  const float* ln_pr_b  = (const float*)d_in[5];
  const float* w_q      = (const float*)d_in[6];
  const float* w_k      = (const float*)d_in[7];
  const float* w_v      = (const float*)d_in[8];
  const float* w_g      = (const float*)d_in[9];
  const float* b_g      = (const float*)d_in[10];
  const float* w_b      = (const float*)d_in[11];
  const float* b_b      = (const float*)d_in[12];
  const float* w_o      = (const float*)d_in[13];
  const float* b_o      = (const float*)d_in[14];
  float* out = (float*)d_out;

  char* ws = (char*)d_ws;
  ushort* m   = (ushort*)(ws + 0);            // 16,777,216
  ushort* qb  = (ushort*)(ws + 16777216ull);  // 16,777,216
  ushort* kb  = (ushort*)(ws + 33554432ull);  // 16,777,216
  ushort* vb  = (ushort*)(ws + 50331648ull);  // 16,777,216
  ushort* gb  = (ushort*)(ws + 67108864ull);  // 16,777,216
  float*  bi  = (float*) (ws + 83886080ull);  //  2,097,152
  ushort* ob  = (ushort*)(ws + 85983232ull);  // 16,777,216
  ushort* Wt5 = (ushort*)(ws + 102760448ull); //    655,360

  prologue_kernel<<<9296, 256, 0, stream>>>(
      msa, ln_msa_g, ln_msa_b, m, pair, ln_pr_g, ln_pr_b, w_b, b_b, bi,
      w_q, w_k, w_v, w_g, w_o, Wt5);
  proj_mfma<<<dim3(256, 8), 256, 0, stream>>>(m, Wt5, b_g, qb, kb, vb, gb);
  attn_mfma<<<S_DIM * H_DIM, 512, 0, stream>>>(qb, kb, vb, gb, bi, ob);
  out_mfma<<<dim3(256, 2), 256, 0, stream>>>(ob, Wt5 + 4 * 65536, b_o, out);
}